// Round 2
// baseline (485.406 us; speedup 1.0000x reference)
//
#include <hip/hip_runtime.h>
#include <math.h>

#define NGRAPH 1024
#define NN     256
#define NE     2048
#define EMB    39
#define HD     64
#define NT     512    // 8 waves; 2 blocks/CU (LDS 77.5KB) -> 16 waves/CU
#define K1 205
#define K2 164
#define K3 132

// LDS map (bytes):
//  feat   256*64*4 = 65536   swizzled rows: 16B-unit u stored at u^(row&7) -> b128 conflict-free
//  red    1024 f   = 4096    aliases epk (ushort[2048])
//  partial 512 f   = 2048    aliases col (uchar[2048]) + ipart (int[512])
//  cnt    260 i    = 1040
//  cur    256 i    = 1024
//  dinv   256 f    = 1024
//  score  256 f    = 1024
//  feats  128 f    = 512
//  pn      64 f    = 256
//  mlp1    64 f    = 256
//  mlp2    32 f    = 128
//  nodemap 256 s   = 512
//  total = 77456  -> 2 blocks/CU
#define SMEM_BYTES 77456

struct Lds {
    float* feat; float* red; unsigned short* epk;
    float* partial; unsigned char* col; int* ipart;
    int* cnt; int* cur; float* dinv; float* score;
    float* feats; float* pn; float* mlp1; float* mlp2; short* nodemap;
};

// swizzled scalar index: row-major [256][64], 16B unit (j>>2) XORed with row&7
__device__ __forceinline__ int fswz(int row, int k) {
    return row * 64 + (((((k >> 2)) ^ (row & 7)) << 2) | (k & 3));
}

template<int FIN>
__device__ __forceinline__ void layer_body(
    const Lds& S, const int* __restrict__ eb,
    const float* __restrict__ W, const float* __restrict__ bvec,
    const float* __restrict__ pvec, int n, int kkeep, int tid)
{
    const int node = tid & 255;
    const int q    = tid >> 8;       // 0/1: feature half
    const int jo   = q * 32;
    const int jb0  = q * 8;          // 16B-unit base of this half
    const int lane = tid & 63;
    const bool active = node < n;

    // B0: zero counts; wave0 computes pn = p/||p||
    if (tid < 258) S.cnt[tid] = 0;
    if (tid < 64) {
        float pv = pvec[tid];
        float s2 = pv * pv;
        #pragma unroll
        for (int off = 32; off >= 1; off >>= 1) s2 += __shfl_xor(s2, off, 64);
        S.pn[tid] = pv * rsqrtf(s2);
    }
    __syncthreads();

    // B1: pass1 — remap 4 consecutive orig edges/thread; int-atomic degree count
    {
        const int4* src4 = (const int4*)eb;
        const int4* dst4 = (const int4*)(eb + NE);
        int4 sv = src4[tid];
        int4 dv = dst4[tid];
        int ss[4] = { S.nodemap[sv.x], S.nodemap[sv.y], S.nodemap[sv.z], S.nodemap[sv.w] };
        int dd[4] = { S.nodemap[dv.x], S.nodemap[dv.y], S.nodemap[dv.z], S.nodemap[dv.w] };
        unsigned short pk[4];
        #pragma unroll
        for (int t = 0; t < 4; t++) {
            int s = ss[t], d = dd[t];
            pk[t] = 0xFFFFu;
            if ((s | d) >= 0) {                 // both >= 0
                pk[t] = (unsigned short)(s | (d << 8));
                atomicAdd(&S.cnt[d], 1);        // native ds_add_u32
            }
        }
        *(ushort4*)(S.epk + tid * 4) = make_ushort4(pk[0], pk[1], pk[2], pk[3]);
    }
    __syncthreads();

    // B2: fused — exclusive scan of cnt -> offsets, cursors, dinv (counts already in regs)
    if (tid < 64) {
        int base = tid * 4;
        int4 c = *(const int4*)(S.cnt + base);
        int s4 = c.x + c.y + c.z + c.w;
        int x = s4;
        #pragma unroll
        for (int off = 1; off < 64; off <<= 1) {
            int t = __shfl_up(x, off, 64);
            if (tid >= off) x += t;
        }
        int e0 = x - s4;
        int4 off4 = make_int4(e0, e0 + c.x, e0 + c.x + c.y, e0 + c.x + c.y + c.z);
        *(int4*)(S.cnt + base) = off4;
        *(int4*)(S.cur + base) = off4;
        *(float4*)(S.dinv + base) = make_float4(
            rsqrtf((float)(1 + c.x)), rsqrtf((float)(1 + c.y)),
            rsqrtf((float)(1 + c.z)), rsqrtf((float)(1 + c.w)));
        if (tid == 63) S.cnt[256] = x;
    }
    __syncthreads();

    // B4: CSR fill (int-atomic cursors) + h = x@W into registers (x read from LDS, b128)
    {
        ushort4 pk4 = *(const ushort4*)(S.epk + tid * 4);
        unsigned short pks[4] = { pk4.x, pk4.y, pk4.z, pk4.w };
        #pragma unroll
        for (int t = 0; t < 4; t++) {
            unsigned pk = pks[t];
            if (pk != 0xFFFFu) {
                int d = pk >> 8;
                int pos = atomicAdd(&S.cur[d], 1);   // ds_add_rtn_u32
                S.col[pos] = (unsigned char)(pk & 0xFFu);
            }
        }
    }
    float h[32];
    if (active) {
        #pragma unroll
        for (int j = 0; j < 32; j++) h[j] = 0.f;
        const float* Wp   = W + jo;              // wave-uniform half -> scalar loads
        const float* xrow = S.feat + node * 64;
        const int rs = node & 7;
        if (FIN == EMB) {
            #pragma unroll
            for (int u = 0; u < 9; u++) {
                float4 xv = *(const float4*)(xrow + ((u ^ rs) << 2));
                float xs[4] = { xv.x, xv.y, xv.z, xv.w };
                #pragma unroll
                for (int t = 0; t < 4; t++) {
                    int k = u * 4 + t;
                    #pragma unroll
                    for (int j = 0; j < 32; j++) h[j] = fmaf(xs[t], Wp[k * HD + j], h[j]);
                }
            }
            #pragma unroll
            for (int k = 36; k < 39; k++) {      // tail: row has only 39 valid cols
                float xv = xrow[((9 ^ rs) << 2) + (k - 36)];
                #pragma unroll
                for (int j = 0; j < 32; j++) h[j] = fmaf(xv, Wp[k * HD + j], h[j]);
            }
        } else {
            #pragma unroll 4
            for (int u = 0; u < 16; u++) {
                float4 xv = *(const float4*)(xrow + ((u ^ rs) << 2));
                float xs[4] = { xv.x, xv.y, xv.z, xv.w };
                #pragma unroll
                for (int t = 0; t < 4; t++) {
                    int k = u * 4 + t;
                    #pragma unroll
                    for (int j = 0; j < 32; j++) h[j] = fmaf(xs[t], Wp[k * HD + j], h[j]);
                }
            }
        }
    }
    __syncthreads();    // all x reads done before any h write (in-place x->h)

    // B4b: write h rows (b128); h registers DIE here (self-term re-read from LDS in B5)
    if (active) {
        const int rs = node & 7;
        #pragma unroll
        for (int u = 0; u < 8; u++) {
            float4 v;
            v.x = h[u * 4 + 0]; v.y = h[u * 4 + 1]; v.z = h[u * 4 + 2]; v.w = h[u * 4 + 3];
            *(float4*)(S.feat + node * 64 + (((jb0 + u) ^ rs) << 2)) = v;
        }
    }
    __syncthreads();

    // B5: gather agg; self-term h/deg re-read from own LDS row; out = relu(...); score dot
    float out[32];
    float sc = 0.f;
    if (active) {
        int o0 = S.cnt[node], o1 = S.cnt[node + 1];
        float s1[32];
        #pragma unroll
        for (int j = 0; j < 32; j++) s1[j] = 0.f;
        if (o0 < o1) {
            int sN = S.col[o0];                  // prefetch breaks col->hsrc chain
            for (int e = o0; e < o1; e++) {
                int s = sN;
                int en = (e + 1 < o1) ? (e + 1) : e;
                sN = S.col[en];
                float dv = S.dinv[s];
                const float* hs = S.feat + s * 64;
                const int ssz = s & 7;
                #pragma unroll
                for (int u = 0; u < 8; u++) {
                    float4 hv = *(const float4*)(hs + (((jb0 + u) ^ ssz) << 2));
                    s1[u * 4 + 0] = fmaf(dv, hv.x, s1[u * 4 + 0]);
                    s1[u * 4 + 1] = fmaf(dv, hv.y, s1[u * 4 + 1]);
                    s1[u * 4 + 2] = fmaf(dv, hv.z, s1[u * 4 + 2]);
                    s1[u * 4 + 3] = fmaf(dv, hv.w, s1[u * 4 + 3]);
                }
            }
        }
        float dvd = S.dinv[node];
        float invdeg = dvd * dvd;               // 1/deg
        const float* hown = S.feat + node * 64;
        const int rs = node & 7;
        #pragma unroll
        for (int u = 0; u < 8; u++) {
            float4 hv = *(const float4*)(hown + (((jb0 + u) ^ rs) << 2));
            float hs[4] = { hv.x, hv.y, hv.z, hv.w };
            #pragma unroll
            for (int t = 0; t < 4; t++) {
                int j = u * 4 + t;
                float o = fmaf(dvd, s1[j], fmaf(hs[t], invdeg, bvec[jo + j]));
                o = fmaxf(o, 0.f);
                out[j] = o;
                sc = fmaf(o, S.pn[jo + j], sc);
            }
        }
    }
    __syncthreads();    // all feat reads + col reads done -> may overwrite rows / alias partial

    // B5b: out -> own feat row (in place of h); out registers DIE here. Score partial.
    if (active) {
        const int rs = node & 7;
        #pragma unroll
        for (int u = 0; u < 8; u++) {
            float4 v;
            v.x = out[u * 4 + 0]; v.y = out[u * 4 + 1];
            v.z = out[u * 4 + 2]; v.w = out[u * 4 + 3];
            *(float4*)(S.feat + node * 64 + (((jb0 + u) ^ rs) << 2)) = v;
        }
    }
    S.partial[tid] = sc;
    __syncthreads();

    // B7: score = tanh(dot)
    if (tid < 256) S.score[tid] = tanhf(S.partial[tid] + S.partial[tid + 256]);
    __syncthreads();

    // B8: rank by counting (2 threads/node, 128-wide slices; b128 broadcast reads)
    {
        int j0 = q * 128;
        int j1 = (j0 + 128 < n) ? (j0 + 128) : n;
        float si = S.score[node];
        int c = 0;
        int j = j0;
        for (; j + 4 <= j1; j += 4) {
            float4 s4 = *(const float4*)&S.score[j];
            c += (s4.x > si) || (s4.x == si && (j + 0) < node);
            c += (s4.y > si) || (s4.y == si && (j + 1) < node);
            c += (s4.z > si) || (s4.z == si && (j + 2) < node);
            c += (s4.w > si) || (s4.w == si && (j + 3) < node);
        }
        for (; j < j1; j++) {
            float sj = S.score[j];
            c += (sj > si) || (sj == si && j < node);
        }
        S.ipart[tid] = c;
    }
    __syncthreads();

    // B9: rank into cur (cursors dead)
    if (tid < 256) S.cur[tid] = S.ipart[tid] + S.ipart[tid + 256];
    __syncthreads();

    // B10: compose cumulative nodemap; re-read own out row (written at B5b, program order)
    if (tid < 256) {
        int m = S.nodemap[tid];
        if (m >= 0) {
            int r = S.cur[m];
            S.nodemap[tid] = (short)((r < kkeep) ? r : -1);
        }
    }
    float pv[32];
    int r = 0;
    bool keep = false;
    if (active) {
        r = S.cur[node];
        keep = r < kkeep;
        if (keep) {
            const float* orow = S.feat + node * 64;
            const int rs = node & 7;
            #pragma unroll
            for (int u = 0; u < 8; u++) {
                float4 v = *(const float4*)(orow + (((jb0 + u) ^ rs) << 2));
                pv[u * 4 + 0] = v.x; pv[u * 4 + 1] = v.y;
                pv[u * 4 + 2] = v.z; pv[u * 4 + 3] = v.w;
            }
        }
    }
    __syncthreads();    // all own-row reads done before permuted writes

    // B10b: pooled rows written (b128, permuted)
    if (keep) {
        float v = S.score[node];
        const int rr = r & 7;
        #pragma unroll
        for (int u = 0; u < 8; u++) {
            float4 w4;
            w4.x = pv[u * 4 + 0] * v; w4.y = pv[u * 4 + 1] * v;
            w4.z = pv[u * 4 + 2] * v; w4.w = pv[u * 4 + 3] * v;
            *(float4*)(S.feat + r * 64 + (((jb0 + u) ^ rr) << 2)) = w4;
        }
    }
    __syncthreads();

    // B11: readout partials (wave-strided rows, lane=feature; row read = bank permutation)
    {
        int w = tid >> 6;
        float mx = -3.4e38f, sm = 0.f;
        for (int rr = w; rr < kkeep; rr += 8) {
            float v = S.feat[rr * 64 + ((((lane >> 2) ^ (rr & 7)) << 2) | (lane & 3))];
            mx = fmaxf(mx, v);
            sm += v;
        }
        S.red[w * 64 + lane]       = mx;
        S.red[512 + w * 64 + lane] = sm;
    }
    __syncthreads();

    // B12: combine into feats
    if (tid < 64) {
        float mx = S.red[tid], sm = S.red[512 + tid];
        #pragma unroll
        for (int w = 1; w < 8; w++) {
            mx = fmaxf(mx, S.red[w * 64 + tid]);
            sm += S.red[512 + w * 64 + tid];
        }
        S.feats[tid]      += mx;
        S.feats[64 + tid] += sm / (float)kkeep;
    }
    __syncthreads();
}

__global__ __launch_bounds__(NT, 4) void gnn_pool_kernel(
    const float* __restrict__ gx, const int* __restrict__ gedge,
    const float* __restrict__ W1, const float* __restrict__ b1, const float* __restrict__ p1,
    const float* __restrict__ W2, const float* __restrict__ b2, const float* __restrict__ p2,
    const float* __restrict__ W3, const float* __restrict__ b3, const float* __restrict__ p3,
    const float* __restrict__ lW1, const float* __restrict__ lb1,
    const float* __restrict__ lW2, const float* __restrict__ lb2,
    const float* __restrict__ lW3, const float* __restrict__ lb3,
    float* __restrict__ gout)
{
    extern __shared__ __align__(16) char smem_raw[];
    Lds S;
    S.feat    = (float*)smem_raw;                         // 16384 f
    S.red     = S.feat + NN * 64;                         // 1024 f
    S.epk     = (unsigned short*)S.red;                   // alias
    S.partial = S.red + 1024;                             // 512 f
    S.col     = (unsigned char*)S.partial;                // alias
    S.ipart   = (int*)S.partial;                          // alias
    S.cnt     = (int*)(S.partial + 512);                  // 260 i
    S.cur     = S.cnt + 260;                              // 256 i
    S.dinv    = (float*)(S.cur + 256);                    // 256 f
    S.score   = S.dinv + 256;                             // 256 f
    S.feats   = S.score + 256;                            // 128 f
    S.pn      = S.feats + 128;                            // 64 f
    S.mlp1    = S.pn + 64;                                // 64 f
    S.mlp2    = S.mlp1 + 64;                              // 32 f
    S.nodemap = (short*)(S.mlp2 + 32);                    // 256 s

    const int tid = threadIdx.x;
    const int b   = blockIdx.x;
    const int* eb = gedge + (size_t)b * 2 * NE;

    // init: x -> swizzled feat rows (float4 global loads), identity nodemap, zero feats
    {
        const float4* xb4 = (const float4*)(gx + (size_t)b * NN * EMB);
        for (int i = tid; i < (NN * EMB) / 4; i += NT) {   // 2496 vec4
            float4 v = xb4[i];
            int g = i * 4;
            float vs[4] = { v.x, v.y, v.z, v.w };
            #pragma unroll
            for (int t = 0; t < 4; t++) {
                int gg = g + t;
                int nd = gg / EMB;
                int k  = gg - nd * EMB;
                S.feat[fswz(nd, k)] = vs[t];
            }
        }
        if (tid < NN) S.nodemap[tid] = (short)tid;
        if (tid < 2 * HD) S.feats[tid] = 0.f;
    }
    __syncthreads();

    layer_body<EMB>(S, eb, W1, b1, p1, NN, K1, tid);
    layer_body<HD >(S, eb, W2, b2, p2, K1, K2, tid);
    layer_body<HD >(S, eb, W3, b3, p3, K2, K3, tid);

    // final MLP: 128 -> 64 -> 32 -> 1, sigmoid
    if (tid < 64) {
        float a = lb1[tid];
        for (int i = 0; i < 2 * HD; i++) a = fmaf(S.feats[i], lW1[i * 64 + tid], a);
        S.mlp1[tid] = fmaxf(a, 0.f);
    }
    __syncthreads();
    if (tid < 32) {
        float a = lb2[tid];
        for (int i = 0; i < 64; i++) a = fmaf(S.mlp1[i], lW2[i * 32 + tid], a);
        S.mlp2[tid] = fmaxf(a, 0.f);
    }
    __syncthreads();
    if (tid == 0) {
        float a = lb3[0];
        for (int i = 0; i < 32; i++) a = fmaf(S.mlp2[i], lW3[i], a);
        gout[b] = 1.0f / (1.0f + expf(-a));
    }
}

extern "C" void kernel_launch(void* const* d_in, const int* in_sizes, int n_in,
                              void* d_out, int out_size, void* d_ws, size_t ws_size,
                              hipStream_t stream) {
    const float* gx    = (const float*)d_in[0];
    const int*   gedge = (const int*)d_in[1];
    const float* W1 = (const float*)d_in[2];
    const float* b1 = (const float*)d_in[3];
    const float* p1 = (const float*)d_in[4];
    const float* W2 = (const float*)d_in[5];
    const float* b2 = (const float*)d_in[6];
    const float* p2 = (const float*)d_in[7];
    const float* W3 = (const float*)d_in[8];
    const float* b3 = (const float*)d_in[9];
    const float* p3 = (const float*)d_in[10];
    const float* lW1 = (const float*)d_in[11];
    const float* lb1 = (const float*)d_in[12];
    const float* lW2 = (const float*)d_in[13];
    const float* lb2 = (const float*)d_in[14];
    const float* lW3 = (const float*)d_in[15];
    const float* lb3 = (const float*)d_in[16];
    float* gout = (float*)d_out;

    (void)hipFuncSetAttribute((const void*)gnn_pool_kernel,
                              hipFuncAttributeMaxDynamicSharedMemorySize, SMEM_BYTES);

    gnn_pool_kernel<<<NGRAPH, NT, SMEM_BYTES, stream>>>(
        gx, gedge, W1, b1, p1, W2, b2, p2, W3, b3, p3,
        lW1, lb1, lW2, lb2, lW3, lb3, gout);
}

// Round 3
// 268.294 us; speedup vs baseline: 1.8092x; 1.8092x over previous
//
#include <hip/hip_runtime.h>
#include <math.h>

#define NGRAPH 1024
#define NN     256
#define NE     2048
#define EMB    39
#define HD     64
#define NT     512    // 8 waves; 2 blocks/CU (LDS 77.5KB) -> 16 waves/CU
#define K1 205
#define K2 164
#define K3 132

// LDS map (bytes):
//  feat   256*64*4 = 65536   swizzled rows: 16B-unit u stored at u^(row&7) -> b128 conflict-free
//  red    1024 f   = 4096    aliases epk (ushort[2048])
//  partial 512 f   = 2048    aliases col (uchar[2048]) + ipart (int[512])
//  cnt    260 i    = 1040
//  cur    256 i    = 1024
//  dinv   256 f    = 1024
//  score  256 f    = 1024
//  feats  128 f    = 512
//  pn      64 f    = 256
//  mlp1    64 f    = 256
//  mlp2    32 f    = 128
//  nodemap 256 s   = 512
//  total = 77456  -> 2 blocks/CU
#define SMEM_BYTES 77456

struct Lds {
    float* feat; float* red; unsigned short* epk;
    float* partial; unsigned char* col; int* ipart;
    int* cnt; int* cur; float* dinv; float* score;
    float* feats; float* pn; float* mlp1; float* mlp2; short* nodemap;
};

// swizzled scalar index: row-major [256][64], 16B unit (j>>2) XORed with row&7
__device__ __forceinline__ int fswz(int row, int k) {
    return row * 64 + (((((k >> 2)) ^ (row & 7)) << 2) | (k & 3));
}

template<int FIN>
__device__ __forceinline__ void layer_body(
    const Lds& S, const int* __restrict__ eb,
    const float* __restrict__ W, const float* __restrict__ bvec,
    const float* __restrict__ pvec, int n, int kkeep, int tid)
{
    const int node = tid & 255;
    const int q    = tid >> 8;       // 0/1: feature half (wave-uniform at runtime)
    // readfirstlane: compiler can't prove tid>>8 wave-uniform -> without this, W/bvec
    // loads are per-lane global_load_dword (2048 VMEM/thread/layer). Force SGPR base
    // so B4's weights come in via s_load on the scalar pipe.
    const int joU  = __builtin_amdgcn_readfirstlane(q * 32);
    const int jb0  = q * 8;          // 16B-unit base of this half (LDS addrs are per-lane anyway)
    const int lane = tid & 63;
    const bool active = node < n;

    // B0: zero counts; wave0 computes pn = p/||p||
    if (tid < 258) S.cnt[tid] = 0;
    if (tid < 64) {
        float pv = pvec[tid];
        float s2 = pv * pv;
        #pragma unroll
        for (int off = 32; off >= 1; off >>= 1) s2 += __shfl_xor(s2, off, 64);
        S.pn[tid] = pv * rsqrtf(s2);
    }
    __syncthreads();

    // B1: pass1 — remap 4 consecutive orig edges/thread; int-atomic degree count
    {
        const int4* src4 = (const int4*)eb;
        const int4* dst4 = (const int4*)(eb + NE);
        int4 sv = src4[tid];
        int4 dv = dst4[tid];
        int ss[4] = { S.nodemap[sv.x], S.nodemap[sv.y], S.nodemap[sv.z], S.nodemap[sv.w] };
        int dd[4] = { S.nodemap[dv.x], S.nodemap[dv.y], S.nodemap[dv.z], S.nodemap[dv.w] };
        unsigned short pk[4];
        #pragma unroll
        for (int t = 0; t < 4; t++) {
            int s = ss[t], d = dd[t];
            pk[t] = 0xFFFFu;
            if ((s | d) >= 0) {                 // both >= 0
                pk[t] = (unsigned short)(s | (d << 8));
                atomicAdd(&S.cnt[d], 1);        // native ds_add_u32
            }
        }
        *(ushort4*)(S.epk + tid * 4) = make_ushort4(pk[0], pk[1], pk[2], pk[3]);
    }
    __syncthreads();

    // B2: fused — exclusive scan of cnt -> offsets, cursors, dinv (counts already in regs)
    if (tid < 64) {
        int base = tid * 4;
        int4 c = *(const int4*)(S.cnt + base);
        int s4 = c.x + c.y + c.z + c.w;
        int x = s4;
        #pragma unroll
        for (int off = 1; off < 64; off <<= 1) {
            int t = __shfl_up(x, off, 64);
            if (tid >= off) x += t;
        }
        int e0 = x - s4;
        int4 off4 = make_int4(e0, e0 + c.x, e0 + c.x + c.y, e0 + c.x + c.y + c.z);
        *(int4*)(S.cnt + base) = off4;
        *(int4*)(S.cur + base) = off4;
        *(float4*)(S.dinv + base) = make_float4(
            rsqrtf((float)(1 + c.x)), rsqrtf((float)(1 + c.y)),
            rsqrtf((float)(1 + c.z)), rsqrtf((float)(1 + c.w)));
        if (tid == 63) S.cnt[256] = x;
    }
    __syncthreads();

    // B4: CSR fill (int-atomic cursors) + h = x@W into registers (x: b128 LDS, W: s_load)
    {
        ushort4 pk4 = *(const ushort4*)(S.epk + tid * 4);
        unsigned short pks[4] = { pk4.x, pk4.y, pk4.z, pk4.w };
        #pragma unroll
        for (int t = 0; t < 4; t++) {
            unsigned pk = pks[t];
            if (pk != 0xFFFFu) {
                int d = pk >> 8;
                int pos = atomicAdd(&S.cur[d], 1);   // ds_add_rtn_u32
                S.col[pos] = (unsigned char)(pk & 0xFFu);
            }
        }
    }
    float h[32];
    if (active) {
        #pragma unroll
        for (int j = 0; j < 32; j++) h[j] = 0.f;
        const float* Wp   = W + joU;             // SGPR base -> scalar W loads
        const float* xrow = S.feat + node * 64;
        const int rs = node & 7;
        if (FIN == EMB) {
            #pragma unroll
            for (int u = 0; u < 9; u++) {
                float4 xv = *(const float4*)(xrow + ((u ^ rs) << 2));
                float xs[4] = { xv.x, xv.y, xv.z, xv.w };
                #pragma unroll
                for (int t = 0; t < 4; t++) {
                    int k = u * 4 + t;
                    #pragma unroll
                    for (int j = 0; j < 32; j++) h[j] = fmaf(xs[t], Wp[k * HD + j], h[j]);
                }
            }
            #pragma unroll
            for (int k = 36; k < 39; k++) {      // tail: row has only 39 valid cols
                float xv = xrow[((9 ^ rs) << 2) + (k - 36)];
                #pragma unroll
                for (int j = 0; j < 32; j++) h[j] = fmaf(xv, Wp[k * HD + j], h[j]);
            }
        } else {
            #pragma unroll 4
            for (int u = 0; u < 16; u++) {
                float4 xv = *(const float4*)(xrow + ((u ^ rs) << 2));
                float xs[4] = { xv.x, xv.y, xv.z, xv.w };
                #pragma unroll
                for (int t = 0; t < 4; t++) {
                    int k = u * 4 + t;
                    #pragma unroll
                    for (int j = 0; j < 32; j++) h[j] = fmaf(xs[t], Wp[k * HD + j], h[j]);
                }
            }
        }
    }
    __syncthreads();    // all x reads done before any h write (in-place x->h)

    // B4b: write h rows (b128); h registers DIE here (self-term re-read from LDS in B5)
    if (active) {
        const int rs = node & 7;
        #pragma unroll
        for (int u = 0; u < 8; u++) {
            float4 v;
            v.x = h[u * 4 + 0]; v.y = h[u * 4 + 1]; v.z = h[u * 4 + 2]; v.w = h[u * 4 + 3];
            *(float4*)(S.feat + node * 64 + (((jb0 + u) ^ rs) << 2)) = v;
        }
    }
    __syncthreads();

    // B5: gather agg; self-term re-read from own LDS row; out computed IN PLACE of s1
    float s1[32];           // becomes `out` after the epilogue loop (no extra 32-reg array)
    float sc = 0.f;
    if (active) {
        int o0 = S.cnt[node], o1 = S.cnt[node + 1];
        #pragma unroll
        for (int j = 0; j < 32; j++) s1[j] = 0.f;
        if (o0 < o1) {
            int sN = S.col[o0];                  // prefetch breaks col->hsrc chain
            for (int e = o0; e < o1; e++) {
                int s = sN;
                int en = (e + 1 < o1) ? (e + 1) : e;
                sN = S.col[en];
                float dv = S.dinv[s];
                const float* hs = S.feat + s * 64;
                const int ssz = s & 7;
                #pragma unroll
                for (int u = 0; u < 8; u++) {
                    float4 hv = *(const float4*)(hs + (((jb0 + u) ^ ssz) << 2));
                    s1[u * 4 + 0] = fmaf(dv, hv.x, s1[u * 4 + 0]);
                    s1[u * 4 + 1] = fmaf(dv, hv.y, s1[u * 4 + 1]);
                    s1[u * 4 + 2] = fmaf(dv, hv.z, s1[u * 4 + 2]);
                    s1[u * 4 + 3] = fmaf(dv, hv.w, s1[u * 4 + 3]);
                }
            }
        }
        float dvd = S.dinv[node];
        float invdeg = dvd * dvd;               // 1/deg
        const float* bU   = bvec + joU;         // SGPR base -> scalar bias loads
        const float* hown = S.feat + node * 64;
        const int rs = node & 7;
        #pragma unroll
        for (int u = 0; u < 8; u++) {
            float4 hv = *(const float4*)(hown + (((jb0 + u) ^ rs) << 2));
            float hs[4] = { hv.x, hv.y, hv.z, hv.w };
            #pragma unroll
            for (int t = 0; t < 4; t++) {
                int j = u * 4 + t;
                float o = fmaf(dvd, s1[j], fmaf(hs[t], invdeg, bU[j]));
                o = fmaxf(o, 0.f);
                s1[j] = o;                       // in place: s1 is now `out`
                sc = fmaf(o, S.pn[joU + j], sc);
            }
        }
    }
    __syncthreads();    // col + feat reads done -> partial may alias col

    // B6: score partials
    S.partial[tid] = sc;
    __syncthreads();

    // B7: score = tanh(dot)
    if (tid < 256) S.score[tid] = tanhf(S.partial[tid] + S.partial[tid + 256]);
    __syncthreads();

    // B8: rank by counting (2 threads/node, 128-wide slices; b128 broadcast reads)
    {
        int j0 = joU * 4;                        // q*128, scalar
        int j1 = (j0 + 128 < n) ? (j0 + 128) : n;
        float si = S.score[node];
        int c = 0;
        int j = j0;
        for (; j + 4 <= j1; j += 4) {
            float4 s4 = *(const float4*)&S.score[j];
            c += (s4.x > si) || (s4.x == si && (j + 0) < node);
            c += (s4.y > si) || (s4.y == si && (j + 1) < node);
            c += (s4.z > si) || (s4.z == si && (j + 2) < node);
            c += (s4.w > si) || (s4.w == si && (j + 3) < node);
        }
        for (; j < j1; j++) {
            float sj = S.score[j];
            c += (sj > si) || (sj == si && j < node);
        }
        S.ipart[tid] = c;
    }
    __syncthreads();

    // B9: rank into cur (cursors dead)
    if (tid < 256) S.cur[tid] = S.ipart[tid] + S.ipart[tid + 256];
    __syncthreads();

    // B10: compose cumulative nodemap; pooled rows written from out regs (b128, permuted)
    if (tid < 256) {
        int m = S.nodemap[tid];
        if (m >= 0) {
            int r = S.cur[m];
            S.nodemap[tid] = (short)((r < kkeep) ? r : -1);
        }
    }
    if (active) {
        int r = S.cur[node];
        if (r < kkeep) {
            float v = S.score[node];
            const int rr = r & 7;
            #pragma unroll
            for (int u = 0; u < 8; u++) {
                float4 w4;
                w4.x = s1[u * 4 + 0] * v; w4.y = s1[u * 4 + 1] * v;
                w4.z = s1[u * 4 + 2] * v; w4.w = s1[u * 4 + 3] * v;
                *(float4*)(S.feat + r * 64 + (((jb0 + u) ^ rr) << 2)) = w4;
            }
        }
    }
    __syncthreads();

    // B11: readout partials (wave-strided rows, lane=feature; row read = bank permutation)
    {
        int w = tid >> 6;
        float mx = -3.4e38f, sm = 0.f;
        for (int rr = w; rr < kkeep; rr += 8) {
            float v = S.feat[rr * 64 + ((((lane >> 2) ^ (rr & 7)) << 2) | (lane & 3))];
            mx = fmaxf(mx, v);
            sm += v;
        }
        S.red[w * 64 + lane]       = mx;
        S.red[512 + w * 64 + lane] = sm;
    }
    __syncthreads();

    // B12: combine into feats
    if (tid < 64) {
        float mx = S.red[tid], sm = S.red[512 + tid];
        #pragma unroll
        for (int w = 1; w < 8; w++) {
            mx = fmaxf(mx, S.red[w * 64 + tid]);
            sm += S.red[512 + w * 64 + tid];
        }
        S.feats[tid]      += mx;
        S.feats[64 + tid] += sm / (float)kkeep;
    }
    __syncthreads();
}

__global__ __launch_bounds__(NT, 4) void gnn_pool_kernel(
    const float* __restrict__ gx, const int* __restrict__ gedge,
    const float* __restrict__ W1, const float* __restrict__ b1, const float* __restrict__ p1,
    const float* __restrict__ W2, const float* __restrict__ b2, const float* __restrict__ p2,
    const float* __restrict__ W3, const float* __restrict__ b3, const float* __restrict__ p3,
    const float* __restrict__ lW1, const float* __restrict__ lb1,
    const float* __restrict__ lW2, const float* __restrict__ lb2,
    const float* __restrict__ lW3, const float* __restrict__ lb3,
    float* __restrict__ gout)
{
    extern __shared__ __align__(16) char smem_raw[];
    Lds S;
    S.feat    = (float*)smem_raw;                         // 16384 f
    S.red     = S.feat + NN * 64;                         // 1024 f
    S.epk     = (unsigned short*)S.red;                   // alias
    S.partial = S.red + 1024;                             // 512 f
    S.col     = (unsigned char*)S.partial;                // alias
    S.ipart   = (int*)S.partial;                          // alias
    S.cnt     = (int*)(S.partial + 512);                  // 260 i
    S.cur     = S.cnt + 260;                              // 256 i
    S.dinv    = (float*)(S.cur + 256);                    // 256 f
    S.score   = S.dinv + 256;                             // 256 f
    S.feats   = S.score + 256;                            // 128 f
    S.pn      = S.feats + 128;                            // 64 f
    S.mlp1    = S.pn + 64;                                // 64 f
    S.mlp2    = S.mlp1 + 64;                              // 32 f
    S.nodemap = (short*)(S.mlp2 + 32);                    // 256 s

    const int tid = threadIdx.x;
    const int b   = blockIdx.x;
    const int* eb = gedge + (size_t)b * 2 * NE;

    // init: x -> swizzled feat rows (float4 global loads), identity nodemap, zero feats
    {
        const float4* xb4 = (const float4*)(gx + (size_t)b * NN * EMB);
        for (int i = tid; i < (NN * EMB) / 4; i += NT) {   // 2496 vec4
            float4 v = xb4[i];
            int g = i * 4;
            float vs[4] = { v.x, v.y, v.z, v.w };
            #pragma unroll
            for (int t = 0; t < 4; t++) {
                int gg = g + t;
                int nd = gg / EMB;
                int k  = gg - nd * EMB;
                S.feat[fswz(nd, k)] = vs[t];
            }
        }
        if (tid < NN) S.nodemap[tid] = (short)tid;
        if (tid < 2 * HD) S.feats[tid] = 0.f;
    }
    __syncthreads();

    layer_body<EMB>(S, eb, W1, b1, p1, NN, K1, tid);
    layer_body<HD >(S, eb, W2, b2, p2, K1, K2, tid);
    layer_body<HD >(S, eb, W3, b3, p3, K2, K3, tid);

    // final MLP: 128 -> 64 -> 32 -> 1, sigmoid
    if (tid < 64) {
        float a = lb1[tid];
        for (int i = 0; i < 2 * HD; i++) a = fmaf(S.feats[i], lW1[i * 64 + tid], a);
        S.mlp1[tid] = fmaxf(a, 0.f);
    }
    __syncthreads();
    if (tid < 32) {
        float a = lb2[tid];
        for (int i = 0; i < 64; i++) a = fmaf(S.mlp1[i], lW2[i * 32 + tid], a);
        S.mlp2[tid] = fmaxf(a, 0.f);
    }
    __syncthreads();
    if (tid == 0) {
        float a = lb3[0];
        for (int i = 0; i < 32; i++) a = fmaf(S.mlp2[i], lW3[i], a);
        gout[b] = 1.0f / (1.0f + expf(-a));
    }
}

extern "C" void kernel_launch(void* const* d_in, const int* in_sizes, int n_in,
                              void* d_out, int out_size, void* d_ws, size_t ws_size,
                              hipStream_t stream) {
    const float* gx    = (const float*)d_in[0];
    const int*   gedge = (const int*)d_in[1];
    const float* W1 = (const float*)d_in[2];
    const float* b1 = (const float*)d_in[3];
    const float* p1 = (const float*)d_in[4];
    const float* W2 = (const float*)d_in[5];
    const float* b2 = (const float*)d_in[6];
    const float* p2 = (const float*)d_in[7];
    const float* W3 = (const float*)d_in[8];
    const float* b3 = (const float*)d_in[9];
    const float* p3 = (const float*)d_in[10];
    const float* lW1 = (const float*)d_in[11];
    const float* lb1 = (const float*)d_in[12];
    const float* lW2 = (const float*)d_in[13];
    const float* lb2 = (const float*)d_in[14];
    const float* lW3 = (const float*)d_in[15];
    const float* lb3 = (const float*)d_in[16];
    float* gout = (float*)d_out;

    (void)hipFuncSetAttribute((const void*)gnn_pool_kernel,
                              hipFuncAttributeMaxDynamicSharedMemorySize, SMEM_BYTES);

    gnn_pool_kernel<<<NGRAPH, NT, SMEM_BYTES, stream>>>(
        gx, gedge, W1, b1, p1, W2, b2, p2, W3, b3, p3,
        lW1, lb1, lW2, lb2, lW3, lb3, gout);
}